// Round 1
// baseline (409.259 us; speedup 1.0000x reference)
//
#include <hip/hip_runtime.h>
#include <math.h>

#define SCALE 4.0f
#define H 128
#define E 64
#define TMAX 32

__device__ __forceinline__ float fsigmoid(float x) {
    return 1.0f / (1.0f + __expf(-x));
}
__device__ __forceinline__ float ftanh(float x) {
    float ax = fabsf(x);
    float e = __expf(-2.0f * ax);
    float t = (1.0f - e) / (1.0f + e);
    return copysignf(t, x);
}

// One block = 2 scenes (2 selected agents). Thread layout: tid[7] = agent
// slot, tid[0:6] = hidden unit u. Thread (ag,u) computes gates i,f,g,o of
// unit u (rows u, u+128, u+256, u+384 of W_ih/W_hh), carries c[u] in a
// register, shares h via LDS.
__global__ __launch_bounds__(256)
void lstm_disc_kernel(
    const float* __restrict__ observed,
    const float* __restrict__ prediction,
    const int* __restrict__ batch_split,
    const float* __restrict__ W_emb,
    const float* __restrict__ b_emb,
    const float* __restrict__ W_ih,
    const float* __restrict__ W_hh,
    const float* __restrict__ b_ih,
    const float* __restrict__ b_hh,
    const float* __restrict__ W1, const float* __restrict__ b1,
    const float* __restrict__ W2, const float* __restrict__ b2,
    const float* __restrict__ W3, const float* __restrict__ b3,
    float* __restrict__ out,
    int N, int T_obs, int T_total, int n_scenes)
{
    __shared__ float h_lds[2][H];
    __shared__ float px[2][TMAX], py[2][TMAX];
    __shared__ float x1[2][H / 2];
    __shared__ float x2[2][H / 4];

    const int tid = threadIdx.x;
    const int ag  = tid >> 7;      // 0 or 1
    const int u   = tid & 127;     // hidden unit
    const int scene = blockIdx.x * 2 + ag;
    const bool valid = scene < n_scenes;
    const int agent = valid ? batch_split[scene] : 0;

    // Stage this agent's 21-frame track into LDS.
    if (u < T_total) {
        const int t = u;
        const float* src = (t < T_obs)
            ? (observed  + (size_t)t          * N * 2)
            : (prediction + (size_t)(t - T_obs) * N * 2);
        px[ag][t] = src[(size_t)agent * 2 + 0];
        py[ag][t] = src[(size_t)agent * 2 + 1];
    }
    h_lds[ag][u] = 0.0f;

    // Fold the embedding layer into per-gate scalars:
    //   gates[g] = C[g] + a*U0[g] + b*U1[g] + dot(h, W_hh[g])
    // with a = SCALE*vel_x, b = SCALE*vel_y,
    //   U0[g] = sum_k W_ih[g,k] * W_emb[k,0]
    //   U1[g] = sum_k W_ih[g,k] * W_emb[k,1]
    //   C[g]  = b_ih[g] + b_hh[g] + sum_k W_ih[g,k] * b_emb[k]
    float U0[4], U1[4], C[4];
    #pragma unroll
    for (int q = 0; q < 4; ++q) {
        const int g = u + q * H;
        const float* wr = W_ih + (size_t)g * E;
        float s0 = 0.f, s1 = 0.f, sc = 0.f;
        #pragma unroll 8
        for (int k = 0; k < E; ++k) {
            const float w = wr[k];
            s0 += w * W_emb[k * 2 + 0];
            s1 += w * W_emb[k * 2 + 1];
            sc += w * b_emb[k];
        }
        U0[q] = s0;
        U1[q] = s1;
        C[q]  = sc + b_ih[g] + b_hh[g];
    }

    const float4* wrow0 = (const float4*)(W_hh + (size_t)(u + 0 * H) * H);
    const float4* wrow1 = (const float4*)(W_hh + (size_t)(u + 1 * H) * H);
    const float4* wrow2 = (const float4*)(W_hh + (size_t)(u + 2 * H) * H);
    const float4* wrow3 = (const float4*)(W_hh + (size_t)(u + 3 * H) * H);

    float c = 0.0f;
    __syncthreads();

    for (int t = 0; t < T_total - 1; ++t) {
        const float o1x = px[ag][t],     o1y = py[ag][t];
        const float o2x = px[ag][t + 1], o2y = py[ag][t + 1];
        const bool mask = !(isnan(o1x) || isnan(o2x));
        const float a = mask ? SCALE * (o2x - o1x) : 0.0f;
        const float b = mask ? SCALE * (o2y - o1y) : 0.0f;

        float acc0 = C[0] + a * U0[0] + b * U1[0];
        float acc1 = C[1] + a * U0[1] + b * U1[1];
        float acc2 = C[2] + a * U0[2] + b * U1[2];
        float acc3 = C[3] + a * U0[3] + b * U1[3];

        const float4* h4 = (const float4*)h_lds[ag];
        #pragma unroll
        for (int k = 0; k < H / 4; ++k) {
            const float4 hv = h4[k];
            float4 w;
            w = wrow0[k];
            acc0 += hv.x * w.x + hv.y * w.y + hv.z * w.z + hv.w * w.w;
            w = wrow1[k];
            acc1 += hv.x * w.x + hv.y * w.y + hv.z * w.z + hv.w * w.w;
            w = wrow2[k];
            acc2 += hv.x * w.x + hv.y * w.y + hv.z * w.z + hv.w * w.w;
            w = wrow3[k];
            acc3 += hv.x * w.x + hv.y * w.y + hv.z * w.z + hv.w * w.w;
        }

        const float ig = fsigmoid(acc0);
        const float fg = fsigmoid(acc1);
        const float gg = ftanh(acc2);
        const float og = fsigmoid(acc3);
        const float c2 = fg * c + ig * gg;
        const float h2 = og * ftanh(c2);

        __syncthreads();           // everyone done reading h
        if (mask) {
            c = c2;
            h_lds[ag][u] = h2;
        }
        __syncthreads();           // h updated for next step
    }

    // MLP head: 128 -> 64 -> 32 -> 1, all relu.
    if (valid && u < H / 2) {
        const float* wr = W1 + (size_t)u * H;
        float s = b1[u];
        #pragma unroll 8
        for (int k = 0; k < H; ++k) s += h_lds[ag][k] * wr[k];
        x1[ag][u] = fmaxf(s, 0.0f);
    }
    __syncthreads();
    if (valid && u < H / 4) {
        const float* wr = W2 + (size_t)u * (H / 2);
        float s = b2[u];
        #pragma unroll 8
        for (int k = 0; k < H / 2; ++k) s += x1[ag][k] * wr[k];
        x2[ag][u] = fmaxf(s, 0.0f);
    }
    __syncthreads();
    if (valid && u == 0) {
        float s = b3[0];
        #pragma unroll
        for (int k = 0; k < H / 4; ++k) s += x2[ag][k] * W3[k];
        out[scene] = fmaxf(s, 0.0f);
    }
}

extern "C" void kernel_launch(void* const* d_in, const int* in_sizes, int n_in,
                              void* d_out, int out_size, void* d_ws, size_t ws_size,
                              hipStream_t stream) {
    const float* observed   = (const float*)d_in[0];
    const float* prediction = (const float*)d_in[1];
    // d_in[2] = goals (unused by the reference computation)
    const int*   batch_split = (const int*)d_in[3];
    const float* W_emb = (const float*)d_in[4];
    const float* b_emb = (const float*)d_in[5];
    const float* W_ih  = (const float*)d_in[6];
    const float* W_hh  = (const float*)d_in[7];
    const float* b_ih  = (const float*)d_in[8];
    const float* b_hh  = (const float*)d_in[9];
    const float* W1 = (const float*)d_in[10];
    const float* b1 = (const float*)d_in[11];
    const float* W2 = (const float*)d_in[12];
    const float* b2 = (const float*)d_in[13];
    const float* W3 = (const float*)d_in[14];
    const float* b3 = (const float*)d_in[15];
    float* out = (float*)d_out;

    const int N       = in_sizes[2] / 2;              // goals is (N,2)
    const int T_obs   = in_sizes[0] / (2 * N);        // observed (T_obs,N,2)
    const int T_pred  = in_sizes[1] / (2 * N);        // prediction (T_pred,N,2)
    const int T_total = T_obs + T_pred;               // 21
    const int n_scenes = in_sizes[3] - 1;             // batch_split has n+1 entries

    const int nblocks = (n_scenes + 1) / 2;           // 2 scenes per block
    lstm_disc_kernel<<<nblocks, 256, 0, stream>>>(
        observed, prediction, batch_split,
        W_emb, b_emb, W_ih, W_hh, b_ih, b_hh,
        W1, b1, W2, b2, W3, b3,
        out, N, T_obs, T_total, n_scenes);
}

// Round 2
// 169.356 us; speedup vs baseline: 2.4166x; 2.4166x over previous
//
#include <hip/hip_runtime.h>
#include <math.h>

#define SCALE 4.0f
#define H 128
#define E 64
#define TMAX 32

__device__ __forceinline__ float fsigmoid(float x) {
    return 1.0f / (1.0f + __expf(-x));
}
__device__ __forceinline__ float ftanh(float x) {
    float ax = fabsf(x);
    float e = __expf(-2.0f * ax);
    float t = (1.0f - e) / (1.0f + e);
    return copysignf(t, x);
}
// NaN test robust to fast-math folding of isnan().
__device__ __forceinline__ bool is_nanf(float x) {
    return (__float_as_uint(x) & 0x7fffffffu) > 0x7f800000u;
}

// Persistent-RNN layout: block = 512 threads = 2 scenes. Thread r owns
// W_hh row r (128 floats = 128 VGPRs, register-stationary for all 20 steps)
// and computes pre-activation gate r for BOTH scenes each step. h is
// broadcast from LDS (same-address b128 reads = conflict-free broadcast).
// Gate exchange via LDS; c-state lives in registers of threads < 256.
// Embedding layer folded: gates[r] = C[r] + a*U0[r] + b*U1[r] + h.W_hh[r].
__global__ __launch_bounds__(512, 2)
void lstm_disc_kernel(
    const float* __restrict__ observed,
    const float* __restrict__ prediction,
    const int* __restrict__ batch_split,
    const float* __restrict__ W_emb,
    const float* __restrict__ b_emb,
    const float* __restrict__ W_ih,
    const float* __restrict__ W_hh,
    const float* __restrict__ b_ih,
    const float* __restrict__ b_hh,
    const float* __restrict__ W1, const float* __restrict__ b1,
    const float* __restrict__ W2, const float* __restrict__ b2,
    const float* __restrict__ W3, const float* __restrict__ b3,
    float* __restrict__ out,
    int N, int T_obs, int T_total, int n_scenes)
{
    __shared__ __align__(16) float h_lds[2][H];
    __shared__ float g_act[2][4 * H];
    __shared__ float px[2][TMAX], py[2][TMAX];
    __shared__ float x1s[2][H / 2];
    __shared__ float x2s[2][H / 4];

    const int tid = threadIdx.x;
    const int r = tid;          // gate row 0..511
    const int q = r >> 7;       // 0=i, 1=f, 2=g, 3=o
    const int sc0 = blockIdx.x * 2;

    // Stage both scenes' 21-frame tracks into LDS.
    if (tid < 64) {
        const int s = tid >> 5, t = tid & 31;
        const int scene = sc0 + s;
        if (t < T_total && scene < n_scenes) {
            const int agent = batch_split[scene];
            const float* src = (t < T_obs)
                ? (observed   + (size_t)t           * N * 2)
                : (prediction + (size_t)(t - T_obs) * N * 2);
            px[s][t] = src[(size_t)agent * 2 + 0];
            py[s][t] = src[(size_t)agent * 2 + 1];
        }
    }
    if (tid < 256) h_lds[tid >> 7][tid & 127] = 0.0f;

    // Fold the embedding layer into per-row scalars.
    float U0 = 0.f, U1 = 0.f, Cc = 0.f;
    {
        const float* wr = W_ih + (size_t)r * E;
        #pragma unroll 8
        for (int k = 0; k < E; ++k) {
            const float w = wr[k];
            U0 += w * W_emb[2 * k + 0];
            U1 += w * W_emb[2 * k + 1];
            Cc += w * b_emb[k];
        }
        Cc += b_ih[r] + b_hh[r];
    }

    // Register-stationary W_hh row (128 VGPRs).
    float4 w4[H / 4];
    {
        const float4* row = (const float4*)(W_hh + (size_t)r * H);
        #pragma unroll
        for (int k = 0; k < H / 4; ++k) w4[k] = row[k];
    }

    float c_st = 0.0f;   // c[u] for threads < 256 (s = tid>>7, u = tid&127)
    __syncthreads();

    for (int t = 0; t < T_total - 1; ++t) {
        const float o1x0 = px[0][t], o2x0 = px[0][t + 1];
        const float o1x1 = px[1][t], o2x1 = px[1][t + 1];
        const bool m0 = !(is_nanf(o1x0) || is_nanf(o2x0));
        const bool m1 = !(is_nanf(o1x1) || is_nanf(o2x1));
        const float a0  = m0 ? SCALE * (o2x0 - o1x0) : 0.f;
        const float bv0 = m0 ? SCALE * (py[0][t + 1] - py[0][t]) : 0.f;
        const float a1  = m1 ? SCALE * (o2x1 - o1x1) : 0.f;
        const float bv1 = m1 ? SCALE * (py[1][t + 1] - py[1][t]) : 0.f;

        float acc0 = Cc + a0 * U0 + bv0 * U1;
        float acc1 = Cc + a1 * U0 + bv1 * U1;

        const float4* h40 = (const float4*)h_lds[0];
        const float4* h41 = (const float4*)h_lds[1];
        #pragma unroll
        for (int k = 0; k < H / 4; ++k) {
            const float4 w  = w4[k];
            const float4 v0 = h40[k];
            acc0 += v0.x * w.x + v0.y * w.y + v0.z * w.z + v0.w * w.w;
            const float4 v1 = h41[k];
            acc1 += v1.x * w.x + v1.y * w.y + v1.z * w.z + v1.w * w.w;
        }

        const float act0 = (q == 2) ? ftanh(acc0) : fsigmoid(acc0);
        const float act1 = (q == 2) ? ftanh(acc1) : fsigmoid(acc1);
        g_act[0][r] = act0;
        g_act[1][r] = act1;
        __syncthreads();        // gates ready; h reads all done

        if (tid < 256) {
            const int s = tid >> 7, u = tid & 127;
            const float ig = g_act[s][0 * H + u];
            const float fg = g_act[s][1 * H + u];
            const float gg = g_act[s][2 * H + u];
            const float og = g_act[s][3 * H + u];
            const float c2 = fg * c_st + ig * gg;
            const float h2 = og * ftanh(c2);
            const bool m = s ? m1 : m0;
            if (m) { c_st = c2; h_lds[s][u] = h2; }
        }
        __syncthreads();        // h updated for next step
    }

    // MLP head: 128 -> 64 -> 32 -> 1, relu.
    if (tid < 128) {
        const int s = tid >> 6, u = tid & 63;
        const float* wr = W1 + (size_t)u * H;
        float sum = b1[u];
        #pragma unroll 8
        for (int k = 0; k < H; ++k) sum += h_lds[s][k] * wr[k];
        x1s[s][u] = fmaxf(sum, 0.f);
    }
    __syncthreads();
    if (tid < 64) {
        const int s = tid >> 5, u = tid & 31;
        const float* wr = W2 + (size_t)u * (H / 2);
        float sum = b2[u];
        #pragma unroll 8
        for (int k = 0; k < H / 2; ++k) sum += x1s[s][k] * wr[k];
        x2s[s][u] = fmaxf(sum, 0.f);
    }
    __syncthreads();
    if (tid < 2) {
        const int scene = sc0 + tid;
        if (scene < n_scenes) {
            float sum = b3[0];
            #pragma unroll
            for (int k = 0; k < H / 4; ++k) sum += x2s[tid][k] * W3[k];
            out[scene] = fmaxf(sum, 0.f);
        }
    }
}

extern "C" void kernel_launch(void* const* d_in, const int* in_sizes, int n_in,
                              void* d_out, int out_size, void* d_ws, size_t ws_size,
                              hipStream_t stream) {
    const float* observed   = (const float*)d_in[0];
    const float* prediction = (const float*)d_in[1];
    // d_in[2] = goals (unused by the reference computation)
    const int*   batch_split = (const int*)d_in[3];
    const float* W_emb = (const float*)d_in[4];
    const float* b_emb = (const float*)d_in[5];
    const float* W_ih  = (const float*)d_in[6];
    const float* W_hh  = (const float*)d_in[7];
    const float* b_ih  = (const float*)d_in[8];
    const float* b_hh  = (const float*)d_in[9];
    const float* W1 = (const float*)d_in[10];
    const float* b1 = (const float*)d_in[11];
    const float* W2 = (const float*)d_in[12];
    const float* b2 = (const float*)d_in[13];
    const float* W3 = (const float*)d_in[14];
    const float* b3 = (const float*)d_in[15];
    float* out = (float*)d_out;

    const int N       = in_sizes[2] / 2;              // goals is (N,2)
    const int T_obs   = in_sizes[0] / (2 * N);        // observed (T_obs,N,2)
    const int T_total = T_obs + in_sizes[1] / (2 * N);// 21
    const int n_scenes = in_sizes[3] - 1;             // batch_split has n+1 entries

    const int nblocks = (n_scenes + 1) / 2;           // 2 scenes per block
    lstm_disc_kernel<<<nblocks, 512, 0, stream>>>(
        observed, prediction, batch_split,
        W_emb, b_emb, W_ih, W_hh, b_ih, b_hh,
        W1, b1, W2, b2, W3, b3,
        out, N, T_obs, T_total, n_scenes);
}

// Round 3
// 143.285 us; speedup vs baseline: 2.8563x; 1.1820x over previous
//
#include <hip/hip_runtime.h>
#include <math.h>

#define SCALE 4.0f
#define H 128
#define E 64
#define TMAX 32

__device__ __forceinline__ float fsigmoid(float x) {
    return 1.0f / (1.0f + __expf(-x));
}
__device__ __forceinline__ float ftanh(float x) {
    float ax = fabsf(x);
    float e = __expf(-2.0f * ax);
    float t = (1.0f - e) / (1.0f + e);
    return copysignf(t, x);
}
// NaN test robust to fast-math folding of isnan().
__device__ __forceinline__ bool is_nanf(float x) {
    return (__float_as_uint(x) & 0x7fffffffu) > 0x7f800000u;
}
// Broadcast lane l's value of v to all lanes via SGPR (VALU pipe, not LDS).
__device__ __forceinline__ float rl(float v, int l) {
    return __int_as_float(__builtin_amdgcn_readlane(__float_as_int(v), l));
}

// Persistent-RNN, readlane-broadcast variant. Block = 512 threads = 2
// scenes; thread r owns W_hh row r (128 VGPRs, register-stationary).
// Per step, each wave pulls h into its own lanes with 4 ds_read_b32
// (lane i holds h[i], h[64+i] per scene), then broadcasts h[k] via
// v_readlane -> SGPR feeding v_fmac (VALU pipe). This removes the 64
// ds_read_b128/wave/step that made R2 LDS-issue-bound (94us ~= measured
// 12.3k LDS cyc/CU/step).
__global__ __launch_bounds__(512, 2)
void lstm_disc_kernel(
    const float* __restrict__ observed,
    const float* __restrict__ prediction,
    const int* __restrict__ batch_split,
    const float* __restrict__ W_emb,
    const float* __restrict__ b_emb,
    const float* __restrict__ W_ih,
    const float* __restrict__ W_hh,
    const float* __restrict__ b_ih,
    const float* __restrict__ b_hh,
    const float* __restrict__ W1, const float* __restrict__ b1,
    const float* __restrict__ W2, const float* __restrict__ b2,
    const float* __restrict__ W3, const float* __restrict__ b3,
    float* __restrict__ out,
    int N, int T_obs, int T_total, int n_scenes)
{
    __shared__ __align__(16) float h_lds[2][H];
    __shared__ float g_act[2][4 * H];
    __shared__ float px[2][TMAX], py[2][TMAX];
    __shared__ float x1s[2][H / 2];
    __shared__ float x2s[2][H / 4];

    const int tid  = threadIdx.x;     // = gate row r, 0..511
    const int lane = tid & 63;
    const int q    = tid >> 7;        // 0=i, 1=f, 2=g, 3=o (wave-uniform)
    const int sc0  = blockIdx.x * 2;

    // Stage both scenes' 21-frame tracks into LDS.
    if (tid < 64) {
        const int s = tid >> 5, t = tid & 31;
        const int scene = sc0 + s;
        if (t < T_total && scene < n_scenes) {
            const int agent = batch_split[scene];
            const float* src = (t < T_obs)
                ? (observed   + (size_t)t           * N * 2)
                : (prediction + (size_t)(t - T_obs) * N * 2);
            px[s][t] = src[(size_t)agent * 2 + 0];
            py[s][t] = src[(size_t)agent * 2 + 1];
        }
    }

    // Register-stationary W_hh row (128 VGPRs).
    float w[H];
    {
        const float4* row = (const float4*)(W_hh + (size_t)tid * H);
        #pragma unroll
        for (int k = 0; k < H / 4; ++k) {
            const float4 v = row[k];
            w[4 * k + 0] = v.x; w[4 * k + 1] = v.y;
            w[4 * k + 2] = v.z; w[4 * k + 3] = v.w;
        }
    }

    // Fold the embedding layer into per-row scalars:
    //   pre[r] = Cc + a*U0 + b*U1 + h.W_hh[r]
    float U0 = 0.f, U1 = 0.f, Cc = 0.f;
    {
        const float* wr = W_ih + (size_t)tid * E;
        #pragma unroll 8
        for (int k = 0; k < E; ++k) {
            const float wv = wr[k];
            U0 += wv * W_emb[2 * k + 0];
            U1 += wv * W_emb[2 * k + 1];
            Cc += wv * b_emb[k];
        }
        Cc += b_ih[tid] + b_hh[tid];
    }

    // Unified activation: sigmoid(x) = 0.5 + 0.5*tanh(0.5*x); tanh(x) as-is.
    // act = ga * ftanh(asc*acc) + gb, all wave-uniform scalars.
    const float asc = (q == 2) ? 1.0f : 0.5f;
    const float ga  = (q == 2) ? 1.0f : 0.5f;
    const float gb  = (q == 2) ? 0.0f : 0.5f;

    // h held in wave lanes: lane i has h[i] (A) and h[64+i] (B), per scene.
    float hA0 = 0.f, hB0 = 0.f, hA1 = 0.f, hB1 = 0.f;
    float c_st = 0.0f;   // c[u] for threads < 256 (s = tid>>7, u = tid&127)
    __syncthreads();

    for (int t = 0; t < T_total - 1; ++t) {
        const float o1x0 = px[0][t], o2x0 = px[0][t + 1];
        const float o1x1 = px[1][t], o2x1 = px[1][t + 1];
        const bool m0 = !(is_nanf(o1x0) || is_nanf(o2x0));
        const bool m1 = !(is_nanf(o1x1) || is_nanf(o2x1));
        const float a0  = m0 ? SCALE * (o2x0 - o1x0) : 0.f;
        const float bv0 = m0 ? SCALE * (py[0][t + 1] - py[0][t]) : 0.f;
        const float a1  = m1 ? SCALE * (o2x1 - o1x1) : 0.f;
        const float bv1 = m1 ? SCALE * (py[1][t + 1] - py[1][t]) : 0.f;

        float s0a = 0.f, s0b = 0.f, s1a = 0.f, s1b = 0.f;
        #pragma unroll
        for (int k = 0; k < 64; ++k) {
            const float h00 = rl(hA0, k);
            const float h01 = rl(hB0, k);
            const float h10 = rl(hA1, k);
            const float h11 = rl(hB1, k);
            s0a += h00 * w[k];
            s0b += h01 * w[64 + k];
            s1a += h10 * w[k];
            s1b += h11 * w[64 + k];
        }
        const float acc0 = (Cc + a0 * U0 + bv0 * U1) + s0a + s0b;
        const float acc1 = (Cc + a1 * U0 + bv1 * U1) + s1a + s1b;

        g_act[0][tid] = ga * ftanh(asc * acc0) + gb;
        g_act[1][tid] = ga * ftanh(asc * acc1) + gb;
        __syncthreads();          // gates ready

        if (tid < 256) {
            const int s = tid >> 7, u = tid & 127;
            const float ig = g_act[s][0 * H + u];
            const float fg = g_act[s][1 * H + u];
            const float gg = g_act[s][2 * H + u];
            const float og = g_act[s][3 * H + u];
            const float c2 = fg * c_st + ig * gg;
            const float h2 = og * ftanh(c2);
            const bool m = s ? m1 : m0;
            if (m) { c_st = c2; h_lds[s][u] = h2; }
            else if (t == 0) { h_lds[s][u] = 0.0f; }  // ensure defined
        }
        __syncthreads();          // h updated

        hA0 = h_lds[0][lane];
        hB0 = h_lds[0][64 + lane];
        hA1 = h_lds[1][lane];
        hB1 = h_lds[1][64 + lane];
    }

    // MLP head: 128 -> 64 -> 32 -> 1, relu.
    if (tid < 128) {
        const int s = tid >> 6, u = tid & 63;
        const float* wr = W1 + (size_t)u * H;
        float sum = b1[u];
        #pragma unroll 8
        for (int k = 0; k < H; ++k) sum += h_lds[s][k] * wr[k];
        x1s[s][u] = fmaxf(sum, 0.f);
    }
    __syncthreads();
    if (tid < 64) {
        const int s = tid >> 5, u = tid & 31;
        const float* wr = W2 + (size_t)u * (H / 2);
        float sum = b2[u];
        #pragma unroll 8
        for (int k = 0; k < H / 2; ++k) sum += x1s[s][k] * wr[k];
        x2s[s][u] = fmaxf(sum, 0.f);
    }
    __syncthreads();
    if (tid < 2) {
        const int scene = sc0 + tid;
        if (scene < n_scenes) {
            float sum = b3[0];
            #pragma unroll
            for (int k = 0; k < H / 4; ++k) sum += x2s[tid][k] * W3[k];
            out[scene] = fmaxf(sum, 0.f);
        }
    }
}

extern "C" void kernel_launch(void* const* d_in, const int* in_sizes, int n_in,
                              void* d_out, int out_size, void* d_ws, size_t ws_size,
                              hipStream_t stream) {
    const float* observed   = (const float*)d_in[0];
    const float* prediction = (const float*)d_in[1];
    // d_in[2] = goals (unused by the reference computation)
    const int*   batch_split = (const int*)d_in[3];
    const float* W_emb = (const float*)d_in[4];
    const float* b_emb = (const float*)d_in[5];
    const float* W_ih  = (const float*)d_in[6];
    const float* W_hh  = (const float*)d_in[7];
    const float* b_ih  = (const float*)d_in[8];
    const float* b_hh  = (const float*)d_in[9];
    const float* W1 = (const float*)d_in[10];
    const float* b1 = (const float*)d_in[11];
    const float* W2 = (const float*)d_in[12];
    const float* b2 = (const float*)d_in[13];
    const float* W3 = (const float*)d_in[14];
    const float* b3 = (const float*)d_in[15];
    float* out = (float*)d_out;

    const int N       = in_sizes[2] / 2;               // goals is (N,2)
    const int T_obs   = in_sizes[0] / (2 * N);         // observed (T_obs,N,2)
    const int T_total = T_obs + in_sizes[1] / (2 * N); // 21
    const int n_scenes = in_sizes[3] - 1;              // batch_split has n+1 entries

    const int nblocks = (n_scenes + 1) / 2;            // 2 scenes per block
    lstm_disc_kernel<<<nblocks, 512, 0, stream>>>(
        observed, prediction, batch_split,
        W_emb, b_emb, W_ih, W_hh, b_ih, b_hh,
        W1, b1, W2, b2, W3, b3,
        out, N, T_obs, T_total, n_scenes);
}

// Round 4
// 139.079 us; speedup vs baseline: 2.9426x; 1.0302x over previous
//
#include <hip/hip_runtime.h>
#include <math.h>

#define SCALE 4.0f
#define H 128
#define E 64
#define NS 4            // scenes per block
#define TMAX 32

typedef __attribute__((ext_vector_type(8))) short short8;   // 8 bf16 = 4 VGPRs
typedef __attribute__((ext_vector_type(4))) float f32x4;

__device__ __forceinline__ bool is_nanf(float x) {
    return (__float_as_uint(x) & 0x7fffffffu) > 0x7f800000u;
}
__device__ __forceinline__ float rcpf(float x) { return __builtin_amdgcn_rcpf(x); }
__device__ __forceinline__ float sigm(float x) { return rcpf(1.0f + __expf(-x)); }
__device__ __forceinline__ float tanhfast(float x) {
    return fmaf(2.0f, rcpf(1.0f + __expf(-2.0f * x)), -1.0f);
}
// fp32 -> bf16 (RNE) and back.
__device__ __forceinline__ unsigned short bfhi(float f) {
    unsigned u = __float_as_uint(f);
    unsigned r = u + 0x7fffu + ((u >> 16) & 1u);
    return (unsigned short)(r >> 16);
}
__device__ __forceinline__ float bff(unsigned short h) {
    return __uint_as_float(((unsigned)h) << 16);
}

// MFMA persistent-LSTM. Block = 512 threads = NS(4) scenes; 128 blocks.
// gates[512 x NS] = W_hh[512x128] @ h[128 x NS] on the matrix pipe:
//   - W_hh held as register-stationary bf16 A-fragments (hi+lo split),
//   - h kept as bf16 hi/lo in LDS laid out in exact B-fragment order
//     (ds_read_b128 conflict-free),
//   - 3-term product W_hi*h_hi + W_hi*h_lo + W_lo*h_hi ~= fp32 accuracy,
//   - raw pre-acts -> LDS (C-layout scatter), 512 epilogue threads add the
//     folded input term, apply sigma/tanh, update c/h in fp32 regs, write
//     h back as bf16 hi/lo into B-frag order.
__global__ __launch_bounds__(512, 2)
void lstm_disc_kernel(
    const float* __restrict__ observed,
    const float* __restrict__ prediction,
    const int* __restrict__ batch_split,
    const float* __restrict__ W_emb,
    const float* __restrict__ b_emb,
    const float* __restrict__ W_ih,
    const float* __restrict__ W_hh,
    const float* __restrict__ b_ih,
    const float* __restrict__ b_hh,
    const float* __restrict__ W1, const float* __restrict__ b1,
    const float* __restrict__ W2, const float* __restrict__ b2,
    const float* __restrict__ W3, const float* __restrict__ b3,
    float* __restrict__ out,
    int N, int T_obs, int T_total, int n_scenes)
{
    // h as bf16 hi/lo in B-fragment order: [kb][lane][8 shorts].
    __shared__ __align__(16) short hb_hi[4][64][8];
    __shared__ __align__(16) short hb_lo[4][64][8];
    __shared__ float g_raw[512][5];          // +1 pad word -> 2-way max
    __shared__ float h32[NS][H];             // final-step fp32 h for MLP
    __shared__ float px[NS][TMAX], py[NS][TMAX];
    __shared__ float aA[NS][TMAX], bA[NS][TMAX];
    __shared__ int   mA[NS][TMAX];
    __shared__ float x1s[NS][H / 2];
    __shared__ float x2s[NS][H / 4];

    const int tid  = threadIdx.x;
    const int wave = tid >> 6;
    const int lane = tid & 63;
    const int ln15 = lane & 15;     // MFMA m / n / col field
    const int g4   = lane >> 4;     // MFMA quad field
    const int sc0  = blockIdx.x * NS;

    // ---- Prologue: stage tracks, zero h buffers ----
    if (tid < NS * TMAX) {
        const int s = tid >> 5, t = tid & 31;
        const int scene = sc0 + s;
        const int agent = (scene < n_scenes) ? batch_split[scene] : 0;
        if (t < T_total) {
            const float* src = (t < T_obs)
                ? (observed   + (size_t)t           * N * 2)
                : (prediction + (size_t)(t - T_obs) * N * 2);
            px[s][t] = src[(size_t)agent * 2 + 0];
            py[s][t] = src[(size_t)agent * 2 + 1];
        }
    }
    {   // zero hb_hi / hb_lo (2048 shorts each)
        int* zh = (int*)hb_hi;
        int* zl = (int*)hb_lo;
        zh[2 * tid] = 0; zh[2 * tid + 1] = 0;
        zl[2 * tid] = 0; zl[2 * tid + 1] = 0;
    }
    __syncthreads();

    // Per-(scene,step) velocity & mask precompute.
    if (tid < NS * TMAX) {
        const int s = tid >> 5, t = tid & 31;
        if (t < T_total - 1) {
            const bool m = !(is_nanf(px[s][t]) || is_nanf(px[s][t + 1]));
            aA[s][t] = m ? SCALE * (px[s][t + 1] - px[s][t]) : 0.0f;
            bA[s][t] = m ? SCALE * (py[s][t + 1] - py[s][t]) : 0.0f;
            mA[s][t] = m ? 1 : 0;
        }
    }

    // ---- Register-stationary A fragments (W_hh as bf16 hi+lo) ----
    // A[m][k]: m = ln15, k = g4*8 + j, tile (mt, kb) -> rows mt*16+m,
    // cols kb*32 + g4*8 .. +7. mt = wave*4 + i.
    short8 ahi[4][4], alo[4][4];
    #pragma unroll
    for (int i = 0; i < 4; ++i) {
        const int mt = wave * 4 + i;
        #pragma unroll
        for (int kb = 0; kb < 4; ++kb) {
            const float* p = W_hh + (size_t)(mt * 16 + ln15) * H + kb * 32 + g4 * 8;
            short8 h8, l8;
            #pragma unroll
            for (int j = 0; j < 8; ++j) {
                const float f = p[j];
                const unsigned short hb = bfhi(f);
                h8[j] = (short)hb;
                l8[j] = (short)bfhi(f - bff(hb));
            }
            ahi[i][kb] = h8;
            alo[i][kb] = l8;
        }
    }

    // ---- Folded input term, per epilogue-thread identity (u, s) ----
    // pre[u+128q] = raw + Cc[q] + a*U0[q] + b*U1[q]
    const int eu = tid & 127;       // hidden unit
    const int es = tid >> 7;        // scene slot
    float U0r[4], U1r[4], Ccr[4];
    #pragma unroll
    for (int q = 0; q < 4; ++q) {
        const int row = eu + q * H;
        const float* wr = W_ih + (size_t)row * E;
        float s0 = 0.f, s1 = 0.f, sc = 0.f;
        #pragma unroll 8
        for (int k = 0; k < E; ++k) {
            const float wv = wr[k];
            s0 += wv * W_emb[2 * k + 0];
            s1 += wv * W_emb[2 * k + 1];
            sc += wv * b_emb[k];
        }
        U0r[q] = s0; U1r[q] = s1; Ccr[q] = sc + b_ih[row] + b_hh[row];
    }

    float c_st = 0.0f, h_st = 0.0f;
    __syncthreads();

    // ---- Recurrent loop ----
    for (int t = 0; t < T_total - 1; ++t) {
        // B fragments from LDS (conflict-free b128: lane -> 16B).
        short8 bhi[4], blo[4];
        #pragma unroll
        for (int kb = 0; kb < 4; ++kb) {
            bhi[kb] = *(const short8*)&hb_hi[kb][lane][0];
            blo[kb] = *(const short8*)&hb_lo[kb][lane][0];
        }

        f32x4 acc[4];
        #pragma unroll
        for (int i = 0; i < 4; ++i) acc[i] = (f32x4){0.f, 0.f, 0.f, 0.f};

        #pragma unroll
        for (int kb = 0; kb < 4; ++kb) {
            #pragma unroll
            for (int i = 0; i < 4; ++i) {
                acc[i] = __builtin_amdgcn_mfma_f32_16x16x32_bf16(ahi[i][kb], bhi[kb], acc[i], 0, 0, 0);
                acc[i] = __builtin_amdgcn_mfma_f32_16x16x32_bf16(ahi[i][kb], blo[kb], acc[i], 0, 0, 0);
                acc[i] = __builtin_amdgcn_mfma_f32_16x16x32_bf16(alo[i][kb], bhi[kb], acc[i], 0, 0, 0);
            }
        }

        // C-layout scatter of raw pre-acts: col = ln15, row = g4*4 + reg.
        if (ln15 < NS) {
            #pragma unroll
            for (int i = 0; i < 4; ++i) {
                const int rb = (wave * 4 + i) * 16 + g4 * 4;
                g_raw[rb + 0][ln15] = acc[i][0];
                g_raw[rb + 1][ln15] = acc[i][1];
                g_raw[rb + 2][ln15] = acc[i][2];
                g_raw[rb + 3][ln15] = acc[i][3];
            }
        }
        __syncthreads();

        // Epilogue: one (u, s) pair per thread.
        {
            const float a  = aA[es][t];
            const float bv = bA[es][t];
            const int   m  = mA[es][t];
            const float p0 = g_raw[eu + 0 * H][es] + Ccr[0] + a * U0r[0] + bv * U1r[0];
            const float p1 = g_raw[eu + 1 * H][es] + Ccr[1] + a * U0r[1] + bv * U1r[1];
            const float p2 = g_raw[eu + 2 * H][es] + Ccr[2] + a * U0r[2] + bv * U1r[2];
            const float p3 = g_raw[eu + 3 * H][es] + Ccr[3] + a * U0r[3] + bv * U1r[3];
            const float ig = sigm(p0);
            const float fg = sigm(p1);
            const float gg = tanhfast(p2);
            const float og = sigm(p3);
            const float c2 = fg * c_st + ig * gg;
            const float h2 = og * tanhfast(c2);
            if (m) { c_st = c2; h_st = h2; }

            // Write h back as bf16 hi/lo in B-frag order:
            // k = eu: kb = eu>>5, quad = (eu>>3)&3, j = eu&7, lanefield = 16*quad + s.
            const unsigned short hhi = bfhi(h_st);
            const unsigned short hlo = bfhi(h_st - bff(hhi));
            const int kb2 = eu >> 5, q2 = (eu >> 3) & 3, j2 = eu & 7;
            hb_hi[kb2][16 * q2 + es][j2] = (short)hhi;
            hb_lo[kb2][16 * q2 + es][j2] = (short)hlo;
            if (t == T_total - 2) h32[es][eu] = h_st;
        }
        __syncthreads();
    }

    // ---- MLP head: 128 -> 64 -> 32 -> 1, relu ----
    if (tid < NS * (H / 2)) {
        const int s = tid >> 6, u = tid & 63;
        const float* wr = W1 + (size_t)u * H;
        float sum = b1[u];
        #pragma unroll 8
        for (int k = 0; k < H; ++k) sum += h32[s][k] * wr[k];
        x1s[s][u] = fmaxf(sum, 0.f);
    }
    __syncthreads();
    if (tid < NS * (H / 4)) {
        const int s = tid >> 5, u = tid & 31;
        const float* wr = W2 + (size_t)u * (H / 2);
        float sum = b2[u];
        #pragma unroll 8
        for (int k = 0; k < H / 2; ++k) sum += x1s[s][k] * wr[k];
        x2s[s][u] = fmaxf(sum, 0.f);
    }
    __syncthreads();
    if (tid < NS) {
        const int scene = sc0 + tid;
        if (scene < n_scenes) {
            float sum = b3[0];
            #pragma unroll
            for (int k = 0; k < H / 4; ++k) sum += x2s[tid][k] * W3[k];
            out[scene] = fmaxf(sum, 0.f);
        }
    }
}

extern "C" void kernel_launch(void* const* d_in, const int* in_sizes, int n_in,
                              void* d_out, int out_size, void* d_ws, size_t ws_size,
                              hipStream_t stream) {
    const float* observed   = (const float*)d_in[0];
    const float* prediction = (const float*)d_in[1];
    // d_in[2] = goals (unused by the reference computation)
    const int*   batch_split = (const int*)d_in[3];
    const float* W_emb = (const float*)d_in[4];
    const float* b_emb = (const float*)d_in[5];
    const float* W_ih  = (const float*)d_in[6];
    const float* W_hh  = (const float*)d_in[7];
    const float* b_ih  = (const float*)d_in[8];
    const float* b_hh  = (const float*)d_in[9];
    const float* W1 = (const float*)d_in[10];
    const float* b1 = (const float*)d_in[11];
    const float* W2 = (const float*)d_in[12];
    const float* b2 = (const float*)d_in[13];
    const float* W3 = (const float*)d_in[14];
    const float* b3 = (const float*)d_in[15];
    float* out = (float*)d_out;

    const int N       = in_sizes[2] / 2;               // goals is (N,2)
    const int T_obs   = in_sizes[0] / (2 * N);         // observed (T_obs,N,2)
    const int T_total = T_obs + in_sizes[1] / (2 * N); // 21
    const int n_scenes = in_sizes[3] - 1;              // batch_split has n+1 entries

    const int nblocks = (n_scenes + NS - 1) / NS;      // 4 scenes per block
    lstm_disc_kernel<<<nblocks, 512, 0, stream>>>(
        observed, prediction, batch_split,
        W_emb, b_emb, W_ih, W_hh, b_ih, b_hh,
        W1, b1, W2, b2, W3, b3,
        out, N, T_obs, T_total, n_scenes);
}

// Round 5
// 134.119 us; speedup vs baseline: 3.0515x; 1.0370x over previous
//
#include <hip/hip_runtime.h>
#include <math.h>

#define SCALE 4.0f
#define H 128
#define E 64
#define NS 4            // scenes per block
#define TMAX 32

typedef __attribute__((ext_vector_type(8))) short short8;   // 8 bf16 = 4 VGPRs
typedef __attribute__((ext_vector_type(4))) float f32x4;

__device__ __forceinline__ bool is_nanf(float x) {
    return (__float_as_uint(x) & 0x7fffffffu) > 0x7f800000u;
}
__device__ __forceinline__ float rcpf(float x) { return __builtin_amdgcn_rcpf(x); }
__device__ __forceinline__ float sigm(float x) { return rcpf(1.0f + __expf(-x)); }
__device__ __forceinline__ float tanhfast(float x) {
    return fmaf(2.0f, rcpf(1.0f + __expf(-2.0f * x)), -1.0f);
}
// fp32 -> bf16 (RNE) and back.
__device__ __forceinline__ unsigned short bfhi(float f) {
    unsigned u = __float_as_uint(f);
    unsigned r = u + 0x7fffu + ((u >> 16) & 1u);
    return (unsigned short)(r >> 16);
}
__device__ __forceinline__ float bff(unsigned short h) {
    return __uint_as_float(((unsigned)h) << 16);
}

// MFMA persistent-LSTM, single-barrier-per-step variant.
// Block = 512 threads = NS(4) scenes; 128 blocks; 1 block/CU.
//
// Key layout trick vs R4: wave w owns M-tiles {q*8+w, q=0..3} = all four
// gate rows of hidden units w*16..w*16+15. After MFMA, the i/f/g/o
// pre-acts of unit u sit in the SAME wave -> no LDS round trip, no 2nd
// barrier. B columns carry scene (col & 3) via broadcast reads, so C-lane
// (g4, ln15=4a+s) does the epilogue for unit w*16+g4*4+a, scene s: all 64
// lanes active, one c-state float per lane. h exchange is parity
// double-buffered bf16 hi/lo in B-fragment order -> ONE barrier per step.
__global__ __launch_bounds__(512, 2)
void lstm_disc_kernel(
    const float* __restrict__ observed,
    const float* __restrict__ prediction,
    const int* __restrict__ batch_split,
    const float* __restrict__ W_emb,
    const float* __restrict__ b_emb,
    const float* __restrict__ W_ih,
    const float* __restrict__ W_hh,
    const float* __restrict__ b_ih,
    const float* __restrict__ b_hh,
    const float* __restrict__ W1, const float* __restrict__ b1,
    const float* __restrict__ W2, const float* __restrict__ b2,
    const float* __restrict__ W3, const float* __restrict__ b3,
    float* __restrict__ out,
    int N, int T_obs, int T_total, int n_scenes)
{
    // h as bf16 hi/lo, parity double-buffered, B-fragment order [kb][lane][8].
    __shared__ __align__(16) short hb_hi[2][4][64][8];
    __shared__ __align__(16) short hb_lo[2][4][64][8];
    __shared__ float h32[NS][H];             // final-step fp32 h for MLP
    __shared__ float px[NS][TMAX], py[NS][TMAX];
    __shared__ float aA[NS][TMAX], bA[NS][TMAX];
    __shared__ int   mA[NS][TMAX];
    __shared__ float x1s[NS][H / 2];
    __shared__ float x2s[NS][H / 4];

    const int tid  = threadIdx.x;
    const int wave = tid >> 6;
    const int lane = tid & 63;
    const int ln15 = lane & 15;     // MFMA m / col field
    const int g4   = lane >> 4;     // MFMA quad field
    const int es   = ln15 & 3;      // epilogue scene
    const int ea   = ln15 >> 2;     // epilogue reg index
    const int eu   = wave * 16 + g4 * 4 + ea;   // epilogue hidden unit
    const int sc0  = blockIdx.x * NS;

    // ---- Prologue: stage tracks, zero h buffers ----
    if (tid < NS * TMAX) {
        const int s = tid >> 5, t = tid & 31;
        const int scene = sc0 + s;
        const int agent = (scene < n_scenes) ? batch_split[scene] : 0;
        if (t < T_total) {
            const float* src = (t < T_obs)
                ? (observed   + (size_t)t           * N * 2)
                : (prediction + (size_t)(t - T_obs) * N * 2);
            px[s][t] = src[(size_t)agent * 2 + 0];
            py[s][t] = src[(size_t)agent * 2 + 1];
        }
    }
    {   // zero both parities of hb_hi / hb_lo (4096 ints total)
        int* zh = (int*)hb_hi;
        int* zl = (int*)hb_lo;
        #pragma unroll
        for (int j = 0; j < 4; ++j) {
            zh[tid + 512 * j] = 0;
            zl[tid + 512 * j] = 0;
        }
    }
    __syncthreads();

    // Per-(scene,step) velocity & mask precompute.
    if (tid < NS * TMAX) {
        const int s = tid >> 5, t = tid & 31;
        if (t < T_total - 1) {
            const bool m = !(is_nanf(px[s][t]) || is_nanf(px[s][t + 1]));
            aA[s][t] = m ? SCALE * (px[s][t + 1] - px[s][t]) : 0.0f;
            bA[s][t] = m ? SCALE * (py[s][t + 1] - py[s][t]) : 0.0f;
            mA[s][t] = m ? 1 : 0;
        }
    }

    // ---- Register-stationary A fragments (W_hh as bf16 hi+lo) ----
    // Wave w, gate q -> M-tile q*8+w (rows (q*8+w)*16 + ln15).
    // A[m=ln15][k = g4*8 + j], tile column block kb.
    short8 ahi[4][4], alo[4][4];
    #pragma unroll
    for (int q = 0; q < 4; ++q) {
        const int mt = q * 8 + wave;
        #pragma unroll
        for (int kb = 0; kb < 4; ++kb) {
            const float* p = W_hh + (size_t)(mt * 16 + ln15) * H + kb * 32 + g4 * 8;
            short8 h8, l8;
            #pragma unroll
            for (int j = 0; j < 8; ++j) {
                const float f = p[j];
                const unsigned short hb = bfhi(f);
                h8[j] = (short)hb;
                l8[j] = (short)bfhi(f - bff(hb));
            }
            ahi[q][kb] = h8;
            alo[q][kb] = l8;
        }
    }

    // ---- Folded input term for this lane's epilogue unit eu ----
    // pre[eu+128q] = raw + Ccr[q] + a*U0r[q] + b*U1r[q]
    float U0r[4], U1r[4], Ccr[4];
    #pragma unroll
    for (int q = 0; q < 4; ++q) {
        const int row = eu + q * H;
        const float* wr = W_ih + (size_t)row * E;
        float s0 = 0.f, s1 = 0.f, sc = 0.f;
        #pragma unroll 8
        for (int k = 0; k < E; ++k) {
            const float wv = wr[k];
            s0 += wv * W_emb[2 * k + 0];
            s1 += wv * W_emb[2 * k + 1];
            sc += wv * b_emb[k];
        }
        U0r[q] = s0; U1r[q] = s1; Ccr[q] = sc + b_ih[row] + b_hh[row];
    }

    // h-writeback coordinates for unit eu, scene es (B-frag order).
    const int wb_kb = eu >> 5;
    const int wb_ln = 16 * ((eu >> 3) & 3) + es;
    const int wb_j  = eu & 7;

    float c_st = 0.0f, h_st = 0.0f;
    __syncthreads();

    // ---- Recurrent loop: ONE barrier per step ----
    for (int t = 0; t < T_total - 1; ++t) {
        const int rp = t & 1, wp = rp ^ 1;

        // Step inputs (LDS, broadcast within scene groups).
        const float aa = aA[es][t];
        const float bb = bA[es][t];
        const int   mm = mA[es][t];

        // B fragments: scene (ln15&3) replicated across the 4 col-copies.
        // Same-address broadcast within each quad -> conflict-free b128.
        short8 bhi[4], blo[4];
        #pragma unroll
        for (int kb = 0; kb < 4; ++kb) {
            bhi[kb] = *(const short8*)&hb_hi[rp][kb][16 * g4 + es][0];
            blo[kb] = *(const short8*)&hb_lo[rp][kb][16 * g4 + es][0];
        }

        // 8 accumulator chains (<=8 deep) to stay off MFMA dep-latency.
        f32x4 accA[4], accB[4];
        #pragma unroll
        for (int q = 0; q < 4; ++q) {
            accA[q] = (f32x4){0.f, 0.f, 0.f, 0.f};
            accB[q] = (f32x4){0.f, 0.f, 0.f, 0.f};
        }
        #pragma unroll
        for (int kb = 0; kb < 4; ++kb) {
            #pragma unroll
            for (int q = 0; q < 4; ++q)
                accA[q] = __builtin_amdgcn_mfma_f32_16x16x32_bf16(ahi[q][kb], bhi[kb], accA[q], 0, 0, 0);
        }
        #pragma unroll
        for (int kb = 0; kb < 4; ++kb) {
            #pragma unroll
            for (int q = 0; q < 4; ++q) {
                accA[q] = __builtin_amdgcn_mfma_f32_16x16x32_bf16(ahi[q][kb], blo[kb], accA[q], 0, 0, 0);
                accB[q] = __builtin_amdgcn_mfma_f32_16x16x32_bf16(alo[q][kb], bhi[kb], accB[q], 0, 0, 0);
            }
        }

        // In-lane epilogue: this lane's C element is reg 'ea' of each gate.
        const float p0 = accA[0][ea] + accB[0][ea] + Ccr[0] + aa * U0r[0] + bb * U1r[0];
        const float p1 = accA[1][ea] + accB[1][ea] + Ccr[1] + aa * U0r[1] + bb * U1r[1];
        const float p2 = accA[2][ea] + accB[2][ea] + Ccr[2] + aa * U0r[2] + bb * U1r[2];
        const float p3 = accA[3][ea] + accB[3][ea] + Ccr[3] + aa * U0r[3] + bb * U1r[3];
        const float ig = sigm(p0);
        const float fg = sigm(p1);
        const float gg = tanhfast(p2);
        const float og = sigm(p3);
        const float c2 = fg * c_st + ig * gg;
        const float h2 = og * tanhfast(c2);
        if (mm) { c_st = c2; h_st = h2; }

        // Write h (bf16 hi/lo) into the OTHER parity buffer.
        const unsigned short hhi = bfhi(h_st);
        const unsigned short hlo = bfhi(h_st - bff(hhi));
        hb_hi[wp][wb_kb][wb_ln][wb_j] = (short)hhi;
        hb_lo[wp][wb_kb][wb_ln][wb_j] = (short)hlo;
        if (t == T_total - 2) h32[es][eu] = h_st;

        __syncthreads();
    }

    // ---- MLP head: 128 -> 64 -> 32 -> 1, relu ----
    if (tid < NS * (H / 2)) {
        const int s = tid >> 6, u = tid & 63;
        const float* wr = W1 + (size_t)u * H;
        float sum = b1[u];
        #pragma unroll 8
        for (int k = 0; k < H; ++k) sum += h32[s][k] * wr[k];
        x1s[s][u] = fmaxf(sum, 0.f);
    }
    __syncthreads();
    if (tid < NS * (H / 4)) {
        const int s = tid >> 5, u = tid & 31;
        const float* wr = W2 + (size_t)u * (H / 2);
        float sum = b2[u];
        #pragma unroll 8
        for (int k = 0; k < H / 2; ++k) sum += x1s[s][k] * wr[k];
        x2s[s][u] = fmaxf(sum, 0.f);
    }
    __syncthreads();
    if (tid < NS) {
        const int scene = sc0 + tid;
        if (scene < n_scenes) {
            float sum = b3[0];
            #pragma unroll
            for (int k = 0; k < H / 4; ++k) sum += x2s[tid][k] * W3[k];
            out[scene] = fmaxf(sum, 0.f);
        }
    }
}

extern "C" void kernel_launch(void* const* d_in, const int* in_sizes, int n_in,
                              void* d_out, int out_size, void* d_ws, size_t ws_size,
                              hipStream_t stream) {
    const float* observed   = (const float*)d_in[0];
    const float* prediction = (const float*)d_in[1];
    // d_in[2] = goals (unused by the reference computation)
    const int*   batch_split = (const int*)d_in[3];
    const float* W_emb = (const float*)d_in[4];
    const float* b_emb = (const float*)d_in[5];
    const float* W_ih  = (const float*)d_in[6];
    const float* W_hh  = (const float*)d_in[7];
    const float* b_ih  = (const float*)d_in[8];
    const float* b_hh  = (const float*)d_in[9];
    const float* W1 = (const float*)d_in[10];
    const float* b1 = (const float*)d_in[11];
    const float* W2 = (const float*)d_in[12];
    const float* b2 = (const float*)d_in[13];
    const float* W3 = (const float*)d_in[14];
    const float* b3 = (const float*)d_in[15];
    float* out = (float*)d_out;

    const int N       = in_sizes[2] / 2;               // goals is (N,2)
    const int T_obs   = in_sizes[0] / (2 * N);         // observed (T_obs,N,2)
    const int T_total = T_obs + in_sizes[1] / (2 * N); // 21
    const int n_scenes = in_sizes[3] - 1;              // batch_split has n+1 entries

    const int nblocks = (n_scenes + NS - 1) / NS;      // 4 scenes per block
    lstm_disc_kernel<<<nblocks, 512, 0, stream>>>(
        observed, prediction, batch_split,
        W_emb, b_emb, W_ih, W_hh, b_ih, b_hh,
        W1, b1, W2, b2, W3, b3,
        out, N, T_obs, T_total, n_scenes);
}

// Round 6
// 118.070 us; speedup vs baseline: 3.4662x; 1.1359x over previous
//
#include <hip/hip_runtime.h>
#include <math.h>

#define SCALE 4.0f
#define H 128
#define E 64
#define NS 4            // scenes per block
#define TMAX 32

// d_ws layout (bytes):
//   [0      , 131072)  A-frag hi: short8 [w(8)][q(4)][kb(4)][lane(64)]
//   [131072 , 262144)  A-frag lo: same order
//   [262144 , 270336)  Uc: float4 {U0,U1,Cc,0} per gate row r (512 rows)
#define WS_LO_OFF  131072
#define WS_UC_OFF  262144

typedef __attribute__((ext_vector_type(8))) short short8;   // 8 bf16 = 4 VGPRs
typedef __attribute__((ext_vector_type(4))) float f32x4;

__device__ __forceinline__ bool is_nanf(float x) {
    return (__float_as_uint(x) & 0x7fffffffu) > 0x7f800000u;
}
__device__ __forceinline__ float rcpf(float x) { return __builtin_amdgcn_rcpf(x); }
__device__ __forceinline__ float sigm(float x) { return rcpf(1.0f + __expf(-x)); }
__device__ __forceinline__ float tanhfast(float x) {
    return fmaf(2.0f, rcpf(1.0f + __expf(-2.0f * x)), -1.0f);
}
// fp32 -> bf16 (RNE) and back.
__device__ __forceinline__ unsigned short bfhi(float f) {
    unsigned u = __float_as_uint(f);
    unsigned r = u + 0x7fffu + ((u >> 16) & 1u);
    return (unsigned short)(r >> 16);
}
__device__ __forceinline__ float bff(unsigned short h) {
    return __uint_as_float(((unsigned)h) << 16);
}

// ---------------- Pre-swizzle kernel ----------------
// Threads 0..8191: one per A-fragment slot (w,q,kb,lane): read 8 floats of
// W_hh (contiguous 32B), write bf16 hi/lo short8 to ws in fragment order
// (coalesced 16B stores). Threads 8192..8703: one per gate row r, compute
// folded input terms U0/U1/Cc.
__global__ __launch_bounds__(256)
void prep_kernel(const float* __restrict__ W_hh,
                 const float* __restrict__ W_ih,
                 const float* __restrict__ W_emb,
                 const float* __restrict__ b_emb,
                 const float* __restrict__ b_ih,
                 const float* __restrict__ b_hh,
                 char* __restrict__ ws)
{
    const int gid = blockIdx.x * 256 + threadIdx.x;
    if (gid < 8192) {
        const int lane = gid & 63;
        const int kb   = (gid >> 6) & 3;
        const int q    = (gid >> 8) & 3;
        const int w    = gid >> 10;
        const int mt   = q * 8 + w;
        const int row  = mt * 16 + (lane & 15);
        const int col0 = kb * 32 + (lane >> 4) * 8;
        const float* p = W_hh + (size_t)row * H + col0;
        short8 h8, l8;
        #pragma unroll
        for (int j = 0; j < 8; ++j) {
            const float f = p[j];
            const unsigned short hb = bfhi(f);
            h8[j] = (short)hb;
            l8[j] = (short)bfhi(f - bff(hb));
        }
        *(short8*)(ws + (size_t)gid * 16)             = h8;
        *(short8*)(ws + WS_LO_OFF + (size_t)gid * 16) = l8;
    } else if (gid < 8192 + 512) {
        const int r = gid - 8192;
        const float* wr = W_ih + (size_t)r * E;
        float s0 = 0.f, s1 = 0.f, sc = 0.f;
        #pragma unroll 8
        for (int k = 0; k < E; ++k) {
            const float wv = wr[k];
            s0 += wv * W_emb[2 * k + 0];
            s1 += wv * W_emb[2 * k + 1];
            sc += wv * b_emb[k];
        }
        f32x4 v = {s0, s1, sc + b_ih[r] + b_hh[r], 0.0f};
        *(f32x4*)(ws + WS_UC_OFF + (size_t)r * 16) = v;
    }
}

// ---------------- Main kernel ----------------
// MFMA persistent-LSTM, one barrier per step (see R5 comments). Changes vs
// R5: (1) A-fragments + folded input terms loaded COALESCED from the
// pre-swizzled ws (R5's scattered scalar prologue was ~40us of the 58);
// (2) h rows relabelled row = q2 + 4*scene so the 16 b128 B-read addresses
// are only 2-way per bank (free) instead of 4-way.
__global__ __launch_bounds__(512, 2)
void lstm_disc_kernel(
    const float* __restrict__ observed,
    const float* __restrict__ prediction,
    const int* __restrict__ batch_split,
    const char* __restrict__ ws,
    const float* __restrict__ W1, const float* __restrict__ b1,
    const float* __restrict__ W2, const float* __restrict__ b2,
    const float* __restrict__ W3, const float* __restrict__ b3,
    float* __restrict__ out,
    int N, int T_obs, int T_total, int n_scenes)
{
    // h as bf16 hi/lo, parity double-buffered, rows = q2 + 4*scene.
    __shared__ __align__(16) short hb_hi[2][4][16][8];
    __shared__ __align__(16) short hb_lo[2][4][16][8];
    __shared__ float h32[NS][H];             // final-step fp32 h for MLP
    __shared__ float px[NS][TMAX], py[NS][TMAX];
    __shared__ float aA[NS][TMAX], bA[NS][TMAX];
    __shared__ int   mA[NS][TMAX];
    __shared__ float x1s[NS][H / 2];
    __shared__ float x2s[NS][H / 4];

    const int tid  = threadIdx.x;
    const int wave = tid >> 6;
    const int lane = tid & 63;
    const int ln15 = lane & 15;     // MFMA m / col field
    const int g4   = lane >> 4;     // MFMA quad field
    const int es   = ln15 & 3;      // epilogue scene
    const int ea   = ln15 >> 2;     // epilogue reg index
    const int eu   = wave * 16 + g4 * 4 + ea;   // epilogue hidden unit
    const int sc0  = blockIdx.x * NS;

    // ---- Prologue ----
    if (tid < NS * TMAX) {
        const int s = tid >> 5, t = tid & 31;
        const int scene = sc0 + s;
        const int agent = (scene < n_scenes) ? batch_split[scene] : 0;
        if (t < T_total) {
            const float* src = (t < T_obs)
                ? (observed   + (size_t)t           * N * 2)
                : (prediction + (size_t)(t - T_obs) * N * 2);
            px[s][t] = src[(size_t)agent * 2 + 0];
            py[s][t] = src[(size_t)agent * 2 + 1];
        }
    }
    {   // zero both parities of hb_hi / hb_lo (512 ints each array)
        int* zh = (int*)hb_hi;
        int* zl = (int*)hb_lo;
        if (tid < 512) { zh[tid] = 0; zl[tid] = 0; }
    }
    __syncthreads();

    if (tid < NS * TMAX) {
        const int s = tid >> 5, t = tid & 31;
        if (t < T_total - 1) {
            const bool m = !(is_nanf(px[s][t]) || is_nanf(px[s][t + 1]));
            aA[s][t] = m ? SCALE * (px[s][t + 1] - px[s][t]) : 0.0f;
            bA[s][t] = m ? SCALE * (py[s][t + 1] - py[s][t]) : 0.0f;
            mA[s][t] = m ? 1 : 0;
        }
    }

    // Register-stationary A fragments: coalesced dwordx4 from ws.
    short8 ahi[4][4], alo[4][4];
    #pragma unroll
    for (int q = 0; q < 4; ++q) {
        #pragma unroll
        for (int kb = 0; kb < 4; ++kb) {
            const size_t idx = ((size_t)((wave * 4 + q) * 4 + kb) * 64 + lane) * 16;
            ahi[q][kb] = *(const short8*)(ws + idx);
            alo[q][kb] = *(const short8*)(ws + WS_LO_OFF + idx);
        }
    }

    // Folded input terms for this lane's epilogue unit eu.
    float U0r[4], U1r[4], Ccr[4];
    #pragma unroll
    for (int q = 0; q < 4; ++q) {
        const f32x4 v = *(const f32x4*)(ws + WS_UC_OFF + (size_t)(eu + q * H) * 16);
        U0r[q] = v[0]; U1r[q] = v[1]; Ccr[q] = v[2];
    }

    // h-writeback coordinates for unit eu, scene es: row = q2 + 4*es.
    const int wb_kb = eu >> 5;
    const int wb_ln = ((eu >> 3) & 3) + 4 * es;
    const int wb_j  = eu & 7;

    float c_st = 0.0f, h_st = 0.0f;
    __syncthreads();

    // ---- Recurrent loop: ONE barrier per step ----
    for (int t = 0; t < T_total - 1; ++t) {
        const int rp = t & 1, wp = rp ^ 1;

        const float aa = aA[es][t];
        const float bb = bA[es][t];
        const int   mm = mA[es][t];

        // B fragments: row g4 + 4*scene; same-address broadcast within each
        // 4-lane group, 16 distinct addrs at 2-way banks (free).
        short8 bhi[4], blo[4];
        #pragma unroll
        for (int kb = 0; kb < 4; ++kb) {
            bhi[kb] = *(const short8*)&hb_hi[rp][kb][g4 + 4 * es][0];
            blo[kb] = *(const short8*)&hb_lo[rp][kb][g4 + 4 * es][0];
        }

        f32x4 accA[4], accB[4];
        #pragma unroll
        for (int q = 0; q < 4; ++q) {
            accA[q] = (f32x4){0.f, 0.f, 0.f, 0.f};
            accB[q] = (f32x4){0.f, 0.f, 0.f, 0.f};
        }
        #pragma unroll
        for (int kb = 0; kb < 4; ++kb) {
            #pragma unroll
            for (int q = 0; q < 4; ++q)
                accA[q] = __builtin_amdgcn_mfma_f32_16x16x32_bf16(ahi[q][kb], bhi[kb], accA[q], 0, 0, 0);
        }
        #pragma unroll
        for (int kb = 0; kb < 4; ++kb) {
            #pragma unroll
            for (int q = 0; q < 4; ++q) {
                accA[q] = __builtin_amdgcn_mfma_f32_16x16x32_bf16(ahi[q][kb], blo[kb], accA[q], 0, 0, 0);
                accB[q] = __builtin_amdgcn_mfma_f32_16x16x32_bf16(alo[q][kb], bhi[kb], accB[q], 0, 0, 0);
            }
        }

        // In-lane epilogue: this lane's C element is reg 'ea' of each gate.
        const float p0 = accA[0][ea] + accB[0][ea] + Ccr[0] + aa * U0r[0] + bb * U1r[0];
        const float p1 = accA[1][ea] + accB[1][ea] + Ccr[1] + aa * U0r[1] + bb * U1r[1];
        const float p2 = accA[2][ea] + accB[2][ea] + Ccr[2] + aa * U0r[2] + bb * U1r[2];
        const float p3 = accA[3][ea] + accB[3][ea] + Ccr[3] + aa * U0r[3] + bb * U1r[3];
        const float ig = sigm(p0);
        const float fg = sigm(p1);
        const float gg = tanhfast(p2);
        const float og = sigm(p3);
        const float c2 = fg * c_st + ig * gg;
        const float h2 = og * tanhfast(c2);
        if (mm) { c_st = c2; h_st = h2; }

        const unsigned short hhi = bfhi(h_st);
        const unsigned short hlo = bfhi(h_st - bff(hhi));
        hb_hi[wp][wb_kb][wb_ln][wb_j] = (short)hhi;
        hb_lo[wp][wb_kb][wb_ln][wb_j] = (short)hlo;
        if (t == T_total - 2) h32[es][eu] = h_st;

        __syncthreads();
    }

    // ---- MLP head: 128 -> 64 -> 32 -> 1, relu ----
    if (tid < NS * (H / 2)) {
        const int s = tid >> 6, u = tid & 63;
        const float4* wr = (const float4*)(W1 + (size_t)u * H);
        const float4* hv = (const float4*)h32[s];
        float sum = b1[u];
        #pragma unroll
        for (int k = 0; k < H / 4; ++k) {
            const float4 w = wr[k], h = hv[k];
            sum += h.x * w.x + h.y * w.y + h.z * w.z + h.w * w.w;
        }
        x1s[s][u] = fmaxf(sum, 0.f);
    }
    __syncthreads();
    if (tid < NS * (H / 4)) {
        const int s = tid >> 5, u = tid & 31;
        const float4* wr = (const float4*)(W2 + (size_t)u * (H / 2));
        const float4* xv = (const float4*)x1s[s];
        float sum = b2[u];
        #pragma unroll
        for (int k = 0; k < H / 8; ++k) {
            const float4 w = wr[k], x = xv[k];
            sum += x.x * w.x + x.y * w.y + x.z * w.z + x.w * w.w;
        }
        x2s[s][u] = fmaxf(sum, 0.f);
    }
    __syncthreads();
    if (tid < NS) {
        const int scene = sc0 + tid;
        if (scene < n_scenes) {
            float sum = b3[0];
            #pragma unroll
            for (int k = 0; k < H / 4; ++k) sum += x2s[tid][k] * W3[k];
            out[scene] = fmaxf(sum, 0.f);
        }
    }
}

extern "C" void kernel_launch(void* const* d_in, const int* in_sizes, int n_in,
                              void* d_out, int out_size, void* d_ws, size_t ws_size,
                              hipStream_t stream) {
    const float* observed   = (const float*)d_in[0];
    const float* prediction = (const float*)d_in[1];
    // d_in[2] = goals (unused by the reference computation)
    const int*   batch_split = (const int*)d_in[3];
    const float* W_emb = (const float*)d_in[4];
    const float* b_emb = (const float*)d_in[5];
    const float* W_ih  = (const float*)d_in[6];
    const float* W_hh  = (const float*)d_in[7];
    const float* b_ih  = (const float*)d_in[8];
    const float* b_hh  = (const float*)d_in[9];
    const float* W1 = (const float*)d_in[10];
    const float* b1 = (const float*)d_in[11];
    const float* W2 = (const float*)d_in[12];
    const float* b2 = (const float*)d_in[13];
    const float* W3 = (const float*)d_in[14];
    const float* b3 = (const float*)d_in[15];
    float* out = (float*)d_out;

    const int N       = in_sizes[2] / 2;               // goals is (N,2)
    const int T_obs   = in_sizes[0] / (2 * N);         // observed (T_obs,N,2)
    const int T_total = T_obs + in_sizes[1] / (2 * N); // 21
    const int n_scenes = in_sizes[3] - 1;              // batch_split has n+1 entries

    prep_kernel<<<36, 256, 0, stream>>>(
        W_hh, W_ih, W_emb, b_emb, b_ih, b_hh, (char*)d_ws);

    const int nblocks = (n_scenes + NS - 1) / NS;      // 4 scenes per block
    lstm_disc_kernel<<<nblocks, 512, 0, stream>>>(
        observed, prediction, batch_split, (const char*)d_ws,
        W1, b1, W2, b2, W3, b3,
        out, N, T_obs, T_total, n_scenes);
}